// Round 3
// baseline (2959.386 us; speedup 1.0000x reference)
//
#include <hip/hip_runtime.h>
#include <math.h>

#define BB 64
#define PP 196
#define TT 32
#define ENCD 2048
#define ATTN 512
#define HIDD 512
#define VOC 10000

// ---------------- d_out scratch (floats): logits region is dead until the final GEMM ----------------
constexpr size_t OUT_ENCMAP = 0;                                   // [12544][512]  = 6,422,528
constexpr size_t OUT_GEMB   = OUT_ENCMAP + (size_t)BB*PP*ATTN;     // [2048 j][2048 m] = 4,194,304
constexpr size_t OUT_WCOMB  = OUT_GEMB + (size_t)2048*2048;        // [2048 j][2560 k] = 5,242,880
constexpr size_t OUT_GPART  = OUT_WCOMB + (size_t)2048*2560;       // [16][2048][64]  = 2,097,152 (end 17,956,864 < 20,480,000)
// ---------------- d_ws (floats): 1,552,640 = 6.2 MB ----------------
constexpr size_t WS_HALL = 0;                                      // [32][64][512] = 1,048,576
constexpr size_t WS_HT   = WS_HALL + (size_t)TT*BB*HIDD;           // 2 x [128 k4][64 b][4] = 65,536
constexpr size_t WS_XB   = WS_HT + (size_t)2*32768;                // 2 x [64 b][2560 k]   = 327,680
constexpr size_t WS_C2   = WS_XB + (size_t)2*163840;               // 2 x [512 j][64 b]    = 65,536
constexpr size_t WS_DEC  = WS_C2 + (size_t)2*32768;                // [64][512] = 32,768
constexpr size_t WS_E    = WS_DEC + (size_t)32768;                 // [64][196] = 12,544

__device__ __forceinline__ float tanh_fast(float x){
    float e = __expf(2.f*x);
    return 1.f - 2.f/(e + 1.f);
}
__device__ __forceinline__ float sigm(float x){
    return 1.f/(1.f + __expf(-x));
}

// zero h0 (hT slot0 + xB slot0 h-part) and c0 (c2 slot0)
__global__ __launch_bounds__(256) void k_init(float* __restrict__ ws){
    int i = blockIdx.x*256 + threadIdx.x;   // grid 128 -> 32768
    if (i < 32768){
        ws[WS_HT + i] = 0.f;
        ws[WS_C2 + i] = 0.f;
        int b = i >> 9, jh = i & 511;
        ws[WS_XB + (size_t)b*2560 + 2048 + jh] = 0.f;
    }
}

// pack Wcomb[j][0:2048] = W_ih[j][0:2048]; Wcomb[j][2048:2560] = W_hh[j][:]
__global__ __launch_bounds__(256) void k_packw(
    const float* __restrict__ Wih, const float* __restrict__ Whh, float* __restrict__ Wc){
    int j = blockIdx.x;                      // 2048
    for (int k = threadIdx.x; k < 2560; k += 256)
        Wc[(size_t)j*2560 + k] = (k < 2048) ? Wih[(size_t)j*2560 + k]
                                            : Whh[(size_t)j*512 + (k-2048)];
}

// ---------------- generic 128x64 fp32 tiled GEMM ----------------
// MODE 0: enc_map = enc[12544][2048] @ We[512][2048]^T + be          -> C[m][512]
// MODE 1: Gemb2[j][m] = W_ih[j][2048:2560] . emb[cap(m)][:] + b_ih[j]+b_hh[j]
//         (A = W_ih rows j, B-operand = gathered emb rows, C [2048 j][2048 m])
// MODE 2: logits: A = h_all[2048][512], W = Wf[10000][512], C -> out[(b*T+t)*V+n] + bf
// MODE 3: gates partial: A = Wcomb[2048][2560], W-op = xB[64][2560],
//         K-slice = blockIdx.z*160..+160, C -> Gpart[z][j][b] (no bias)
template<int MODE>
__global__ __launch_bounds__(256) void k_gemm(
    const float* __restrict__ A, const float* __restrict__ W,
    const float* __restrict__ b0, const float* __restrict__ b1,
    const int* __restrict__ caps, float* __restrict__ C)
{
    constexpr int LDA  = (MODE==0)?2048 : (MODE==1)?2560 : (MODE==2)?512 : 2560;
    constexpr int AOFF = (MODE==1)?2048 : 0;
    constexpr int LDW  = (MODE==0)?2048 : (MODE==3)?2560 : 512;
    constexpr int KLEN = (MODE==0)?2048 : (MODE==3)?160 : 512;

    __shared__ __align__(16) float As[32][132];
    __shared__ __align__(16) float Bs[32][68];

    const int tid = threadIdx.x;
    const int m0 = blockIdx.y * 128;
    const int n0 = blockIdx.x * 64;
    const int tx = tid & 15, ty = tid >> 4;
    const int kbase = (MODE==3) ? (int)blockIdx.z * 160 : 0;

    float acc[8][4];
    #pragma unroll
    for (int i=0;i<8;i++)
        #pragma unroll
        for (int j=0;j<4;j++) acc[i][j] = 0.f;

    for (int k0 = kbase; k0 < kbase + KLEN; k0 += 32){
        #pragma unroll
        for (int r=0;r<16;r++){
            int idx = tid + r*256;
            int m = idx >> 5, k = idx & 31;
            As[k][m] = A[(size_t)(m0+m)*LDA + AOFF + k0 + k];
        }
        #pragma unroll
        for (int r=0;r<8;r++){
            int idx = tid + r*256;
            int n = idx >> 5, k = idx & 31;
            float v;
            if constexpr (MODE==1){
                int gm = n0 + n;                       // gm = t*64 + b
                int cap = caps[(gm & 63)*TT + (gm >> 6)];
                v = W[(size_t)cap*512 + k0 + k];
            } else if constexpr (MODE==2){
                v = ((n0+n) < VOC) ? W[(size_t)(n0+n)*512 + k0 + k] : 0.f;
            } else {
                v = W[(size_t)(n0+n)*LDW + k0 + k];
            }
            Bs[k][n] = v;
        }
        __syncthreads();
        #pragma unroll
        for (int k=0;k<32;k++){
            float av[8], bw[4];
            *(float4*)&av[0] = *(const float4*)&As[k][ty*8];
            *(float4*)&av[4] = *(const float4*)&As[k][ty*8+4];
            *(float4*)&bw[0] = *(const float4*)&Bs[k][tx*4];
            #pragma unroll
            for (int i=0;i<8;i++)
                #pragma unroll
                for (int j=0;j<4;j++)
                    acc[i][j] = fmaf(av[i], bw[j], acc[i][j]);
        }
        __syncthreads();
    }

    const int nb = n0 + tx*4;
    #pragma unroll
    for (int i=0;i<8;i++){
        int m = m0 + ty*8 + i;
        if constexpr (MODE==0){
            float4 o;
            o.x = acc[i][0]+b0[nb+0]; o.y = acc[i][1]+b0[nb+1];
            o.z = acc[i][2]+b0[nb+2]; o.w = acc[i][3]+b0[nb+3];
            *(float4*)&C[(size_t)m*512 + nb] = o;
        } else if constexpr (MODE==1){
            float bias = b0[m] + b1[m];               // per-j bias
            float4 o;
            o.x = acc[i][0]+bias; o.y = acc[i][1]+bias;
            o.z = acc[i][2]+bias; o.w = acc[i][3]+bias;
            *(float4*)&C[(size_t)m*2048 + nb] = o;
        } else if constexpr (MODE==2){
            if (nb < VOC){                             // VOC % 4 == 0, no straddle
                int b = m & 63, t = m >> 6;
                float4 o;
                o.x = acc[i][0]+b0[nb+0]; o.y = acc[i][1]+b0[nb+1];
                o.z = acc[i][2]+b0[nb+2]; o.w = acc[i][3]+b0[nb+3];
                *(float4*)&C[((size_t)(b*TT + t))*VOC + nb] = o;
            }
        } else {
            float* Cz = C + (size_t)blockIdx.z*2048*64;
            float4 o; o.x=acc[i][0]; o.y=acc[i][1]; o.z=acc[i][2]; o.w=acc[i][3];
            *(float4*)&Cz[(size_t)m*64 + nb] = o;
        }
    }
}

// ---------------- per-step: dec = h @ Wd^T + bd  (grid 64) ----------------
__global__ __launch_bounds__(256) void k_dec(
    const float* __restrict__ hT, const float* __restrict__ Wd,
    const float* __restrict__ bd, float* __restrict__ dec)
{
    __shared__ __align__(16) float wl[8][512];
    const int tid = threadIdx.x;
    const int n0 = blockIdx.x * 8;
    #pragma unroll
    for (int r=0;r<16;r++){
        int idx = tid + r*256;
        int n = idx >> 9, k = idx & 511;
        wl[n][k] = Wd[(size_t)(n0+n)*512 + k];
    }
    __syncthreads();
    const int b = tid & 63, nn = tid >> 6;   // cols nn, nn+4
    float a0 = 0.f, a1 = 0.f;
    #pragma unroll 4
    for (int k4=0;k4<128;k4++){
        float4 a  = *(const float4*)&hT[k4*256 + b*4];
        float4 w0 = *(const float4*)&wl[nn][k4*4];
        float4 w1 = *(const float4*)&wl[nn+4][k4*4];
        a0 = fmaf(a.x,w0.x, fmaf(a.y,w0.y, fmaf(a.z,w0.z, fmaf(a.w,w0.w, a0))));
        a1 = fmaf(a.x,w1.x, fmaf(a.y,w1.y, fmaf(a.z,w1.z, fmaf(a.w,w1.w, a1))));
    }
    dec[b*512 + n0 + nn]     = a0 + bd[n0 + nn];
    dec[b*512 + n0 + nn + 4] = a1 + bd[n0 + nn + 4];
}

// ---------------- per-step: e[b,p] = Wa . tanh(enc_map[b,p,:] + dec[b,:]) + ba  (grid 7x64) ----
__global__ __launch_bounds__(256) void k_e(
    const float* __restrict__ enc_map, const float* __restrict__ dec,
    const float* __restrict__ Wa, const float* __restrict__ ba,
    float* __restrict__ e_ws)
{
    __shared__ __align__(16) float dl[512];
    __shared__ __align__(16) float wal[512];
    __shared__ float part[28][9];
    const int tid = threadIdx.x;
    const int b = blockIdx.y, pc = blockIdx.x;
    dl[tid]      = dec[b*512 + tid];
    dl[tid+256]  = dec[b*512 + 256 + tid];
    wal[tid]     = Wa[tid];
    wal[tid+256] = Wa[tid+256];
    __syncthreads();
    const int pl = tid >> 3, seg = tid & 7;
    if (pl < 28){
        int p = pc*28 + pl;
        const float* er = enc_map + ((size_t)b*PP + p)*512 + seg*64;
        float s = 0.f;
        #pragma unroll 4
        for (int i=0;i<16;i++){
            float4 em = *(const float4*)&er[i*4];
            float4 dv = *(const float4*)&dl[seg*64 + i*4];
            float4 wv = *(const float4*)&wal[seg*64 + i*4];
            s = fmaf(tanh_fast(em.x+dv.x), wv.x, s);
            s = fmaf(tanh_fast(em.y+dv.y), wv.y, s);
            s = fmaf(tanh_fast(em.z+dv.z), wv.z, s);
            s = fmaf(tanh_fast(em.w+dv.w), wv.w, s);
        }
        part[pl][seg] = s;
    }
    __syncthreads();
    if (tid < 28){
        float s = 0.f;
        #pragma unroll
        for (int q=0;q<8;q++) s += part[tid][q];
        e_ws[b*PP + pc*28 + tid] = s + ba[0];
    }
}

// ---------------- per-step: softmax (redundant per ec-block) + context (grid 8x64) ----------------
__global__ __launch_bounds__(256) void k_ctx(
    const float* __restrict__ e_ws, const float* __restrict__ enc,
    float* __restrict__ attn_out, float* __restrict__ xB, int t)
{
    __shared__ float red[256];
    __shared__ float al[200];
    const int tid = threadIdx.x, b = blockIdx.y, ecb = blockIdx.x;
    float ev = (tid < PP) ? e_ws[b*PP + tid] : -1e30f;
    red[tid] = ev; __syncthreads();
    for (int s=128;s>0;s>>=1){ if (tid<s) red[tid] = fmaxf(red[tid], red[tid+s]); __syncthreads(); }
    float mx = red[0]; __syncthreads();
    float ex = (tid < PP) ? __expf(ev - mx) : 0.f;
    red[tid] = ex; __syncthreads();
    for (int s=128;s>0;s>>=1){ if (tid<s) red[tid] += red[tid+s]; __syncthreads(); }
    float rs = 1.f / red[0];
    if (tid < PP){
        float a = ex * rs;
        al[tid] = a;
        if (ecb == 0) attn_out[((size_t)b*TT + t)*PP + tid] = a;
    }
    __syncthreads();
    const int ec = ecb*256 + tid;
    const float* eb = enc + (size_t)b*PP*ENCD + ec;
    float s0=0.f, s1=0.f, s2=0.f, s3=0.f;
    #pragma unroll 4
    for (int p=0;p<PP;p+=4){                 // PP = 196 = 4*49, exact
        s0 = fmaf(al[p+0], eb[(size_t)(p+0)*ENCD], s0);
        s1 = fmaf(al[p+1], eb[(size_t)(p+1)*ENCD], s1);
        s2 = fmaf(al[p+2], eb[(size_t)(p+2)*ENCD], s2);
        s3 = fmaf(al[p+3], eb[(size_t)(p+3)*ENCD], s3);
    }
    xB[(size_t)b*2560 + ec] = (s0+s1)+(s2+s3);
}

// ---------------- per-step: sum split-K partials + Gemb + LSTM cell (grid 128) ----------------
__global__ __launch_bounds__(256) void k_cell(
    const float* __restrict__ Gpart, const float* __restrict__ Gemb2,
    const float* __restrict__ c_in, float* __restrict__ c_out,
    float* __restrict__ hT_out, float* __restrict__ xB_next,
    float* __restrict__ h_all, int t)
{
    int i = blockIdx.x*256 + threadIdx.x;    // 32768
    int b = i & 63, jh = i >> 6;
    float g4[4];
    #pragma unroll
    for (int g=0;g<4;g++){
        int j = g*512 + jh;
        float acc = Gemb2[(size_t)j*2048 + t*64 + b];
        #pragma unroll
        for (int ks=0;ks<16;ks++)
            acc += Gpart[(size_t)ks*131072 + (size_t)j*64 + b];
        g4[g] = acc;
    }
    float c_old = c_in[jh*64 + b];
    float cn = sigm(g4[1])*c_old + sigm(g4[0])*tanh_fast(g4[2]);
    float hn = sigm(g4[3])*tanh_fast(cn);
    c_out[jh*64 + b] = cn;
    hT_out[(jh>>2)*256 + b*4 + (jh&3)] = hn;
    xB_next[(size_t)b*2560 + 2048 + jh] = hn;
    h_all[(size_t)t*BB*HIDD + (size_t)b*512 + jh] = hn;
}

// ---------------- finalize h_fin / c_fin ----------------
__global__ __launch_bounds__(256) void k_final(
    const float* __restrict__ h31, const float* __restrict__ c2_fin,
    float* __restrict__ hfin, float* __restrict__ cfin)
{
    int i = blockIdx.x*256 + threadIdx.x;    // 32768
    if (i < 32768){
        hfin[i] = h31[i];
        int b = i >> 9, jh = i & 511;
        cfin[i] = c2_fin[jh*64 + b];
    }
}

extern "C" void kernel_launch(void* const* d_in, const int* in_sizes, int n_in,
                              void* d_out, int out_size, void* d_ws, size_t ws_size,
                              hipStream_t stream)
{
    (void)in_sizes; (void)n_in; (void)out_size; (void)ws_size;
    const float* enc_out = (const float*)d_in[0];
    const int*   caps    = (const int*)  d_in[1];
    const float* emb     = (const float*)d_in[2];
    const float* We      = (const float*)d_in[3];
    const float* be      = (const float*)d_in[4];
    const float* Wd      = (const float*)d_in[5];
    const float* bd      = (const float*)d_in[6];
    const float* Wa      = (const float*)d_in[7];
    const float* ba      = (const float*)d_in[8];
    const float* Wih     = (const float*)d_in[9];
    const float* b_ih    = (const float*)d_in[10];
    const float* Whh     = (const float*)d_in[11];
    const float* b_hh    = (const float*)d_in[12];
    const float* Wf      = (const float*)d_in[13];
    const float* bf      = (const float*)d_in[14];

    float* out = (float*)d_out;
    float* ws  = (float*)d_ws;

    float* enc_map = out + OUT_ENCMAP;
    float* Gemb2   = out + OUT_GEMB;
    float* Wcomb   = out + OUT_WCOMB;
    float* Gpart   = out + OUT_GPART;

    float* h_all = ws + WS_HALL;
    float* hT    = ws + WS_HT;
    float* xB    = ws + WS_XB;
    float* c2    = ws + WS_C2;
    float* dec   = ws + WS_DEC;
    float* e_ws  = ws + WS_E;

    float* out_logits = out;
    float* out_hfin   = out + (size_t)BB*TT*VOC;
    float* out_cfin   = out_hfin + (size_t)BB*HIDD;
    float* out_attn   = out_cfin + (size_t)BB*HIDD;

    k_init<<<dim3(128), dim3(256), 0, stream>>>(ws);
    k_packw<<<dim3(2048), dim3(256), 0, stream>>>(Wih, Whh, Wcomb);
    k_gemm<0><<<dim3(8, 98), dim3(256), 0, stream>>>(enc_out, We, be, nullptr, nullptr, enc_map);
    k_gemm<1><<<dim3(32, 16), dim3(256), 0, stream>>>(Wih, emb, b_ih, b_hh, caps, Gemb2);

    for (int t=0;t<TT;t++){
        int cur = t & 1, nxt = 1 - cur;
        const float* hT_c = hT + (size_t)cur*32768;
        float* xB_c = xB + (size_t)cur*163840;
        k_dec<<<dim3(64), dim3(256), 0, stream>>>(hT_c, Wd, bd, dec);
        k_e<<<dim3(7,64), dim3(256), 0, stream>>>(enc_map, dec, Wa, ba, e_ws);
        k_ctx<<<dim3(8,64), dim3(256), 0, stream>>>(e_ws, enc_out, out_attn, xB_c, t);
        k_gemm<3><<<dim3(1,16,16), dim3(256), 0, stream>>>(Wcomb, xB_c, nullptr, nullptr, nullptr, Gpart);
        k_cell<<<dim3(128), dim3(256), 0, stream>>>(Gpart, Gemb2,
                 c2 + (size_t)cur*32768, c2 + (size_t)nxt*32768,
                 hT + (size_t)nxt*32768, xB + (size_t)nxt*163840,
                 h_all, t);
    }

    k_gemm<2><<<dim3(157, 16), dim3(256), 0, stream>>>(h_all, Wf, bf, nullptr, nullptr, out_logits);
    k_final<<<dim3(128), dim3(256), 0, stream>>>(h_all + (size_t)31*BB*HIDD, c2, out_hfin, out_cfin);
}

// Round 5
// 2219.850 us; speedup vs baseline: 1.3331x; 1.3331x over previous
//
#include <hip/hip_runtime.h>
#include <math.h>

#define BB 64
#define PP 196
#define TT 32
#define ENCD 2048
#define ATTN 512
#define HIDD 512
#define VOC 10000

typedef __attribute__((ext_vector_type(8))) short short8;
typedef __attribute__((ext_vector_type(4))) float f32x4;
typedef unsigned short ushort_t;

// ---------------- d_out scratch (float units); logits region dead until final GEMM ----------------
constexpr size_t OUT_ENCMAP = 0;                                   // fp32 [12544][512]   6,422,528
constexpr size_t OUT_GEMB   = OUT_ENCMAP + (size_t)BB*PP*ATTN;     // bf16 [2048 j][2048 m] -> 2,097,152 slots
constexpr size_t OUT_GPART  = OUT_GEMB + (size_t)2048*2048/2;      // fp32 [16][2048][64]   2,097,152
constexpr size_t OUT_WEB    = OUT_GPART + (size_t)16*2048*64;      // bf16 [512][2048]      524,288 slots
constexpr size_t OUT_WCB    = OUT_WEB + (size_t)512*2048/2;        // bf16 [2048][3072]     3,145,728 slots
// end = 14,286,848 floats = 57.1 MB < 20,480,000 (logits region)

// ---------------- d_ws (float units): 864,512 floats = 3.5 MB ----------------
constexpr size_t WS_HALLB = 0;                                     // bf16 [2048 m][512 j] = 524,288 slots
constexpr size_t WS_HT    = WS_HALLB + (size_t)2048*512/2;         // 2 x fp32 [128 k4][64 b][4]
constexpr size_t WS_XBB   = WS_HT + (size_t)2*32768;               // 2 x bf16 [64 b][2560 k] = 2*81,920 slots
constexpr size_t WS_C2    = WS_XBB + (size_t)2*81920;              // 2 x fp32 [512 j][64 b]
constexpr size_t WS_DEC   = WS_C2 + (size_t)2*32768;               // fp32 [64][512]
constexpr size_t WS_E     = WS_DEC + (size_t)32768;                // fp32 [64][196]

__device__ __forceinline__ float bf2f(ushort_t u){
    union { unsigned v; float f; } x; x.v = ((unsigned)u) << 16; return x.f;
}
__device__ __forceinline__ ushort_t f2bf(float f){
    union { float f; unsigned v; } x; x.f = f;
    unsigned u = x.v;
    return (ushort_t)((u + 0x7FFFu + ((u >> 16) & 1u)) >> 16);   // RNE
}
__device__ __forceinline__ short8 cvt8(const float* p){
    float4 a = *(const float4*)p;
    float4 b = *(const float4*)(p + 4);
    short8 r;
    r[0]=(short)f2bf(a.x); r[1]=(short)f2bf(a.y); r[2]=(short)f2bf(a.z); r[3]=(short)f2bf(a.w);
    r[4]=(short)f2bf(b.x); r[5]=(short)f2bf(b.y); r[6]=(short)f2bf(b.z); r[7]=(short)f2bf(b.w);
    return r;
}
__device__ __forceinline__ float tanh_fast(float x){
    float e = __expf(2.f*x);
    return 1.f - 2.f/(e + 1.f);
}
__device__ __forceinline__ float sigm(float x){
    return 1.f/(1.f + __expf(-x));
}

// zero h0 (hT slot0, xBb slot0 h-part) and c0 (c2 slot0)
__global__ __launch_bounds__(256) void k_init(float* __restrict__ ws){
    int i = blockIdx.x*256 + threadIdx.x;   // grid 128 -> 32768
    if (i < 32768){
        ws[WS_HT + i] = 0.f;
        ws[WS_C2 + i] = 0.f;
        int b = i >> 9, jh = i & 511;
        ((ushort_t*)(ws + WS_XBB))[(size_t)b*2560 + 2048 + jh] = 0;
    }
}

// pack+cvt Wcb[j][0:2048]=W_ih ctx block, [2048:2560]=W_hh, [2560:3072]=W_ih emb block
__global__ __launch_bounds__(256) void k_packwb(
    const float* __restrict__ Wih, const float* __restrict__ Whh, ushort_t* __restrict__ Wcb){
    int j = blockIdx.x;                      // 2048
    for (int k = threadIdx.x; k < 3072; k += 256){
        float v;
        if (k < 2048)      v = Wih[(size_t)j*2560 + k];
        else if (k < 2560) v = Whh[(size_t)j*512 + (k-2048)];
        else               v = Wih[(size_t)j*2560 + 2048 + (k-2560)];
        Wcb[(size_t)j*3072 + k] = f2bf(v);
    }
}

// fp32 -> bf16 bulk convert (n4 = count/4)
__global__ __launch_bounds__(256) void k_cvt(
    const float* __restrict__ src, ushort_t* __restrict__ dst, int n4){
    int i = blockIdx.x*256 + threadIdx.x;
    if (i < n4){
        float4 f = ((const float4*)src)[i];
        unsigned lo = (unsigned)f2bf(f.x) | ((unsigned)f2bf(f.y) << 16);
        unsigned hi = (unsigned)f2bf(f.z) | ((unsigned)f2bf(f.w) << 16);
        uint2 o; o.x = lo; o.y = hi;
        ((uint2*)dst)[i] = o;
    }
}

// ---------------- bf16 MFMA GEMM, 16x16x32, fp32 accum ----------------
// Per block: 4 waves. MODE!=3: 128m x 128n (waves 2x2). MODE==3: 256m x 64n (waves 4x1).
// A/B fragment k-mapping identical (k = kq*8+j, contiguous 16B) -> layout-permutation safe.
// C/D mapping (HW-verified): col = lane&15, row = (lane>>4)*4 + reg.
// MODE 0: enc_map = cvt(enc[12544][2048]) x We_bf[512][2048]^T + be -> fp32 C[m][512]
// MODE 1: Gemb = Wcb[:,2560:3072] x cvt(gather emb[cap(n)][512])^T + bih[j]+bhh[j] -> bf16 C[j][2048]
// MODE 2: logits = h_all_bf[2048][512] x cvt(Wf[10000][512])^T + bf -> fp32 out[(b*32+t)*V+n]
// MODE 3: gates = Wcb[2048][0:2560] x xB_bf[64][2560]^T (K-slice z*160) -> fp32 Gpart[z][j][b]
template<int MODE>
__global__ __launch_bounds__(256) void k_mfma(
    const void* __restrict__ Aptr, const void* __restrict__ Bptr,
    const float* __restrict__ b0, const float* __restrict__ b1,
    const int* __restrict__ caps, void* __restrict__ Cptr)
{
    constexpr int LDA  = (MODE==0)?ENCD : (MODE==2)?512 : 3072;
    constexpr int AOFF = (MODE==1)?2560 : 0;
    constexpr int LDB  = (MODE==0)?ENCD : (MODE==3)?2560 : 512;
    constexpr int KLEN = (MODE==0)?2048 : (MODE==3)?160 : 512;

    const int tid  = threadIdx.x;
    const int wv   = tid >> 6, lane = tid & 63;
    const int l15  = lane & 15, kq = lane >> 4;

    int mbase, nbase;
    if constexpr (MODE==3){ mbase = blockIdx.y*256 + wv*64; nbase = 0; }
    else { mbase = blockIdx.y*128 + (wv>>1)*64; nbase = blockIdx.x*128 + (wv&1)*64; }
    const int kbase = (MODE==3) ? (int)blockIdx.z * KLEN : 0;

    f32x4 acc[4][4];
    #pragma unroll
    for (int mi=0;mi<4;mi++)
        #pragma unroll
        for (int nj=0;nj<4;nj++)
            acc[mi][nj] = (f32x4){0.f,0.f,0.f,0.f};

    int brow[4];
    #pragma unroll
    for (int nj=0;nj<4;nj++){
        int n = nbase + nj*16 + l15;
        if constexpr (MODE==1)      brow[nj] = caps[(n & 63)*TT + (n >> 6)];
        else if constexpr (MODE==2) brow[nj] = (n < VOC) ? n : VOC-1;
        else                        brow[nj] = n;
    }

    for (int k0 = kbase; k0 < kbase + KLEN; k0 += 32){
        short8 af[4], bfr[4];
        #pragma unroll
        for (int mi=0;mi<4;mi++){
            size_t off = (size_t)(mbase + mi*16 + l15)*LDA + AOFF + k0 + kq*8;
            if constexpr (MODE==0) af[mi] = cvt8((const float*)Aptr + off);
            else                   af[mi] = *(const short8*)((const ushort_t*)Aptr + off);
        }
        #pragma unroll
        for (int nj=0;nj<4;nj++){
            size_t off = (size_t)brow[nj]*LDB + k0 + kq*8;
            if constexpr (MODE==1 || MODE==2) bfr[nj] = cvt8((const float*)Bptr + off);
            else                              bfr[nj] = *(const short8*)((const ushort_t*)Bptr + off);
        }
        #pragma unroll
        for (int mi=0;mi<4;mi++)
            #pragma unroll
            for (int nj=0;nj<4;nj++)
                acc[mi][nj] = __builtin_amdgcn_mfma_f32_16x16x32_bf16(af[mi], bfr[nj], acc[mi][nj], 0, 0, 0);
    }

    #pragma unroll
    for (int mi=0;mi<4;mi++){
        #pragma unroll
        for (int r=0;r<4;r++){
            int row = mbase + mi*16 + kq*4 + r;
            #pragma unroll
            for (int nj=0;nj<4;nj++){
                int col = nbase + nj*16 + l15;
                float v = acc[mi][nj][r];
                if constexpr (MODE==0){
                    ((float*)Cptr)[(size_t)row*ATTN + col] = v + b0[col];
                } else if constexpr (MODE==1){
                    ((ushort_t*)Cptr)[(size_t)row*2048 + col] = f2bf(v + b0[row] + b1[row]);
                } else if constexpr (MODE==2){
                    if (col < VOC){
                        int b = row & 63, t = row >> 6;
                        ((float*)Cptr)[((size_t)b*TT + t)*VOC + col] = v + b0[col];
                    }
                } else {
                    ((float*)Cptr)[(size_t)blockIdx.z*2048*64 + (size_t)row*64 + col] = v;
                }
            }
        }
    }
}

// ---------------- per-step: dec = h @ Wd^T + bd  (grid 64) ----------------
__global__ __launch_bounds__(256) void k_dec(
    const float* __restrict__ hT, const float* __restrict__ Wd,
    const float* __restrict__ bd, float* __restrict__ dec)
{
    __shared__ __align__(16) float wl[8][512];
    const int tid = threadIdx.x;
    const int n0 = blockIdx.x * 8;
    #pragma unroll
    for (int r=0;r<16;r++){
        int idx = tid + r*256;
        int n = idx >> 9, k = idx & 511;
        wl[n][k] = Wd[(size_t)(n0+n)*512 + k];
    }
    __syncthreads();
    const int b = tid & 63, nn = tid >> 6;   // cols nn, nn+4
    float a0 = 0.f, a1 = 0.f;
    #pragma unroll 4
    for (int k4=0;k4<128;k4++){
        float4 a  = *(const float4*)&hT[k4*256 + b*4];
        float4 w0 = *(const float4*)&wl[nn][k4*4];
        float4 w1 = *(const float4*)&wl[nn+4][k4*4];
        a0 = fmaf(a.x,w0.x, fmaf(a.y,w0.y, fmaf(a.z,w0.z, fmaf(a.w,w0.w, a0))));
        a1 = fmaf(a.x,w1.x, fmaf(a.y,w1.y, fmaf(a.z,w1.z, fmaf(a.w,w1.w, a1))));
    }
    dec[b*512 + n0 + nn]     = a0 + bd[n0 + nn];
    dec[b*512 + n0 + nn + 4] = a1 + bd[n0 + nn + 4];
}

// ---------------- per-step: e[b,p] = Wa . tanh(enc_map[b,p,:] + dec[b,:]) + ba  (grid 7x64) ----
__global__ __launch_bounds__(256) void k_e(
    const float* __restrict__ enc_map, const float* __restrict__ dec,
    const float* __restrict__ Wa, const float* __restrict__ ba,
    float* __restrict__ e_ws)
{
    __shared__ __align__(16) float dl[512];
    __shared__ __align__(16) float wal[512];
    __shared__ float part[28][9];
    const int tid = threadIdx.x;
    const int b = blockIdx.y, pc = blockIdx.x;
    dl[tid]      = dec[b*512 + tid];
    dl[tid+256]  = dec[b*512 + 256 + tid];
    wal[tid]     = Wa[tid];
    wal[tid+256] = Wa[tid+256];
    __syncthreads();
    const int pl = tid >> 3, seg = tid & 7;
    if (pl < 28){
        int p = pc*28 + pl;
        const float* er = enc_map + ((size_t)b*PP + p)*512 + seg*64;
        float s = 0.f;
        #pragma unroll 4
        for (int i=0;i<16;i++){
            float4 em = *(const float4*)&er[i*4];
            float4 dv = *(const float4*)&dl[seg*64 + i*4];
            float4 wv = *(const float4*)&wal[seg*64 + i*4];
            s = fmaf(tanh_fast(em.x+dv.x), wv.x, s);
            s = fmaf(tanh_fast(em.y+dv.y), wv.y, s);
            s = fmaf(tanh_fast(em.z+dv.z), wv.z, s);
            s = fmaf(tanh_fast(em.w+dv.w), wv.w, s);
        }
        part[pl][seg] = s;
    }
    __syncthreads();
    if (tid < 28){
        float s = 0.f;
        #pragma unroll
        for (int q=0;q<8;q++) s += part[tid][q];
        e_ws[b*PP + pc*28 + tid] = s + ba[0];
    }
}

// ---------------- per-step: softmax (redundant per ec-block) + context (grid 8x64) ----------------
__global__ __launch_bounds__(256) void k_ctx(
    const float* __restrict__ e_ws, const float* __restrict__ enc,
    float* __restrict__ attn_out, ushort_t* __restrict__ xBb, int t)
{
    __shared__ float red[256];
    __shared__ float al[200];
    const int tid = threadIdx.x, b = blockIdx.y, ecb = blockIdx.x;
    float ev = (tid < PP) ? e_ws[b*PP + tid] : -1e30f;
    red[tid] = ev; __syncthreads();
    for (int s=128;s>0;s>>=1){ if (tid<s) red[tid] = fmaxf(red[tid], red[tid+s]); __syncthreads(); }
    float mx = red[0]; __syncthreads();
    float ex = (tid < PP) ? __expf(ev - mx) : 0.f;
    red[tid] = ex; __syncthreads();
    for (int s=128;s>0;s>>=1){ if (tid<s) red[tid] += red[tid+s]; __syncthreads(); }
    float rs = 1.f / red[0];
    if (tid < PP){
        float a = ex * rs;
        al[tid] = a;
        if (ecb == 0) attn_out[((size_t)b*TT + t)*PP + tid] = a;
    }
    __syncthreads();
    const int ec = ecb*256 + tid;
    const float* eb = enc + (size_t)b*PP*ENCD + ec;
    float s0=0.f, s1=0.f, s2=0.f, s3=0.f;
    #pragma unroll 4
    for (int p=0;p<PP;p+=4){                 // PP = 196 = 4*49, exact
        s0 = fmaf(al[p+0], eb[(size_t)(p+0)*ENCD], s0);
        s1 = fmaf(al[p+1], eb[(size_t)(p+1)*ENCD], s1);
        s2 = fmaf(al[p+2], eb[(size_t)(p+2)*ENCD], s2);
        s3 = fmaf(al[p+3], eb[(size_t)(p+3)*ENCD], s3);
    }
    xBb[(size_t)b*2560 + ec] = f2bf((s0+s1)+(s2+s3));
}

// ---------------- per-step: sum split-K partials + Gemb + LSTM cell (grid 128) ----------------
__global__ __launch_bounds__(256) void k_cell(
    const float* __restrict__ Gpart, const ushort_t* __restrict__ Gemb2,
    const float* __restrict__ c_in, float* __restrict__ c_out,
    float* __restrict__ hT_out, ushort_t* __restrict__ xBb_next,
    ushort_t* __restrict__ h_all_b, int t)
{
    int i = blockIdx.x*256 + threadIdx.x;    // 32768
    int b = i & 63, jh = i >> 6;
    float g4[4];
    #pragma unroll
    for (int g=0;g<4;g++){
        int j = g*512 + jh;
        float acc = bf2f(Gemb2[(size_t)j*2048 + t*64 + b]);
        #pragma unroll
        for (int ks=0;ks<16;ks++)
            acc += Gpart[(size_t)ks*131072 + (size_t)j*64 + b];
        g4[g] = acc;
    }
    float c_old = c_in[jh*64 + b];
    float cn = sigm(g4[1])*c_old + sigm(g4[0])*tanh_fast(g4[2]);
    float hn = sigm(g4[3])*tanh_fast(cn);
    c_out[jh*64 + b] = cn;
    hT_out[(jh>>2)*256 + b*4 + (jh&3)] = hn;
    xBb_next[(size_t)b*2560 + 2048 + jh] = f2bf(hn);
    h_all_b[((size_t)t*64 + b)*512 + jh] = f2bf(hn);
}

// ---------------- finalize h_fin / c_fin (exact fp32 path) ----------------
__global__ __launch_bounds__(256) void k_final(
    const float* __restrict__ hT0, const float* __restrict__ c20,
    float* __restrict__ hfin, float* __restrict__ cfin)
{
    int i = blockIdx.x*256 + threadIdx.x;    // 32768
    if (i < 32768){
        int b = i >> 9, jh = i & 511;
        hfin[i] = hT0[(jh>>2)*256 + b*4 + (jh&3)];
        cfin[i] = c20[jh*64 + b];
    }
}

extern "C" void kernel_launch(void* const* d_in, const int* in_sizes, int n_in,
                              void* d_out, int out_size, void* d_ws, size_t ws_size,
                              hipStream_t stream)
{
    (void)in_sizes; (void)n_in; (void)out_size; (void)ws_size;
    const float* enc_out = (const float*)d_in[0];
    const int*   caps    = (const int*)  d_in[1];
    const float* emb     = (const float*)d_in[2];
    const float* We      = (const float*)d_in[3];
    const float* be      = (const float*)d_in[4];
    const float* Wd      = (const float*)d_in[5];
    const float* bd      = (const float*)d_in[6];
    const float* Wa      = (const float*)d_in[7];
    const float* ba      = (const float*)d_in[8];
    const float* Wih     = (const float*)d_in[9];
    const float* b_ih    = (const float*)d_in[10];
    const float* Whh     = (const float*)d_in[11];
    const float* b_hh    = (const float*)d_in[12];
    const float* Wf      = (const float*)d_in[13];
    const float* bf      = (const float*)d_in[14];

    float* out = (float*)d_out;
    float* ws  = (float*)d_ws;

    float*    enc_map = out + OUT_ENCMAP;
    ushort_t* Gemb2b  = (ushort_t*)(out + OUT_GEMB);
    float*    Gpart   = out + OUT_GPART;
    ushort_t* Web     = (ushort_t*)(out + OUT_WEB);
    ushort_t* Wcb     = (ushort_t*)(out + OUT_WCB);

    ushort_t* h_all_b = (ushort_t*)(ws + WS_HALLB);
    float*    hT      = ws + WS_HT;
    ushort_t* xBb     = (ushort_t*)(ws + WS_XBB);
    float*    c2      = ws + WS_C2;
    float*    dec     = ws + WS_DEC;
    float*    e_ws    = ws + WS_E;

    float* out_logits = out;
    float* out_hfin   = out + (size_t)BB*TT*VOC;
    float* out_cfin   = out_hfin + (size_t)BB*HIDD;
    float* out_attn   = out_cfin + (size_t)BB*HIDD;

    k_init<<<dim3(128), dim3(256), 0, stream>>>(ws);
    k_packwb<<<dim3(2048), dim3(256), 0, stream>>>(Wih, Whh, Wcb);
    k_cvt<<<dim3(1024), dim3(256), 0, stream>>>(We, Web, 262144);   // 512*2048/4
    k_mfma<0><<<dim3(4, 98), dim3(256), 0, stream>>>(enc_out, Web, be, nullptr, nullptr, enc_map);
    k_mfma<1><<<dim3(16, 16), dim3(256), 0, stream>>>(Wcb, emb, b_ih, b_hh, caps, Gemb2b);

    for (int t=0;t<TT;t++){
        int cur = t & 1, nxt = 1 - cur;
        const float* hT_c = hT + (size_t)cur*32768;
        ushort_t* xBb_c   = xBb + (size_t)cur*163840;
        k_dec<<<dim3(64), dim3(256), 0, stream>>>(hT_c, Wd, bd, dec);
        k_e<<<dim3(7,64), dim3(256), 0, stream>>>(enc_map, dec, Wa, ba, e_ws);
        k_ctx<<<dim3(8,64), dim3(256), 0, stream>>>(e_ws, enc_out, out_attn, xBb_c, t);
        k_mfma<3><<<dim3(1,8,16), dim3(256), 0, stream>>>(Wcb, xBb_c, nullptr, nullptr, nullptr, Gpart);
        k_cell<<<dim3(128), dim3(256), 0, stream>>>(Gpart, Gemb2b,
                 c2 + (size_t)cur*32768, c2 + (size_t)nxt*32768,
                 hT + (size_t)nxt*32768, xBb + (size_t)nxt*163840,
                 h_all_b, t);
    }

    // logits GEMM overwrites the d_out scratch region; reads only h_all_b (ws) + Wf (input).
    k_mfma<2><<<dim3(79, 16), dim3(256), 0, stream>>>(h_all_b, Wf, bf, nullptr, nullptr, out_logits);
    k_final<<<dim3(128), dim3(256), 0, stream>>>(hT, c2, out_hfin, out_cfin);
}